// Round 9
// baseline (371.880 us; speedup 1.0000x reference)
//
#include <hip/hip_runtime.h>

#define SQ   2048
#define DD   64
#define BK   64
#define BQ   128
#define LDW  72
#define NT   32           // SQ / BK
#define BUFH (BK * LDW)   // halves per LDS buffer (4608)
// Pad LDS to 57344 B so only 2 workgroups fit per CU (3*57 KB > 160 KB):
// caps achievable occupancy at 4 waves/EU -> register budget 128 VGPRs ->
// no incentive for the allocator to squeeze to 64 and spill (R3/R4 bug).
#define SMEM_HALVES 28672

typedef _Float16 f16x8 __attribute__((ext_vector_type(8)));
typedef _Float16 f16x4 __attribute__((ext_vector_type(4)));
typedef _Float16 f16x2 __attribute__((ext_vector_type(2)));
typedef float    f32x4 __attribute__((ext_vector_type(4)));

#if __has_builtin(__builtin_amdgcn_exp2f)
#define EXP2F(x) __builtin_amdgcn_exp2f(x)
#else
#define EXP2F(x) exp2f(x)
#endif

// __builtin_amdgcn_cvt_pkrtz returns __fp16x2; bit-cast to our _Float16x2.
static __device__ __forceinline__ f16x2 PKRTZ(float a, float b) {
    typedef __fp16 fp16x2_t __attribute__((ext_vector_type(2)));
    union { fp16x2_t i; f16x2 o; } u;
    u.i = __builtin_amdgcn_cvt_pkrtz(a, b);
    return u.o;
}
#define MFMA32(a, b, c) __builtin_amdgcn_mfma_f32_16x16x32_f16((a), (b), (c), 0, 0, 0)

// 512 threads = 8 waves: wave (qw = w&3, kh = w>>2) owns q-rows [qw*32, qw*32+32)
// and key half [kh*32, kh*32+32) of every 64-key tile. 16 waves/CU (2 blocks).
__global__ __attribute__((amdgpu_flat_work_group_size(512, 512)))
__attribute__((amdgpu_waves_per_eu(4, 4)))
void attn_fused6(const float* __restrict__ Qg,
                 const float* __restrict__ Kg,
                 const float* __restrict__ Vg,
                 const unsigned char* __restrict__ maskg,
                 float* __restrict__ Og)
{
    __shared__ __align__(16) _Float16 smem[SMEM_HALVES];   // Kl[2] | Vt[2] | pad

    const int tid  = threadIdx.x;
    const int lane = tid & 63;
    const int w    = tid >> 6;       // 0..7
    const int quad = lane >> 4;
    const int l16  = lane & 15;
    const int qw   = w & 3;          // q row-group
    const int kh   = w >> 2;         // key half

    // XCD swizzle: all 16 q-tiles of one (b,h) land on one XCD -> K/V L2 reuse.
    const int n     = blockIdx.x;            // 512 blocks
    const int bh    = (n & 7) + 8 * ((n >> 3) & 3);
    const int qtile = n >> 5;                // 0..15
    const int qBase = qtile * BQ;

    // dk = key length (2048). Fold log2(e) into the scale so exp(x) == exp2(x').
    const float QSCALE = 0.02209708691207961f * 1.4426950408889634f;
    const float MASKED = -1e10f * (0.02209708691207961f * 1.4426950408889634f);

    // ---- Q fragments, pre-scaled: rows qBase + qw*32 + qg*16 + l16 ----
    f16x8 qf[2][2];
#pragma unroll
    for (int qg = 0; qg < 2; ++qg) {
        const float* qrow = Qg + ((size_t)bh * SQ + qBase + qw * 32 + qg * 16 + l16) * DD;
#pragma unroll
        for (int h = 0; h < 2; ++h) {
            float4 a = *(const float4*)(qrow + h * 32 + quad * 8);
            float4 b = *(const float4*)(qrow + h * 32 + quad * 8 + 4);
            union { f16x8 v; f16x2 p[4]; } u;
            u.p[0] = PKRTZ(a.x * QSCALE, a.y * QSCALE);
            u.p[1] = PKRTZ(a.z * QSCALE, a.w * QSCALE);
            u.p[2] = PKRTZ(b.x * QSCALE, b.y * QSCALE);
            u.p[3] = PKRTZ(b.z * QSCALE, b.w * QSCALE);
            qf[qg][h] = u.v;
        }
    }

    f32x4 acc[2][4];   // [qg][dt] partial over this wave's key half
#pragma unroll
    for (int qg = 0; qg < 2; ++qg)
#pragma unroll
        for (int d = 0; d < 4; ++d) acc[qg][d] = (f32x4){0.f, 0.f, 0.f, 0.f};
    float lsum[2] = {0.f, 0.f};

    // staging: waves 0-3 stage K (same map as before at 256t), waves 4-7 stage V
    const bool isK = tid < 256;
    const int t2   = tid & 255;
    const int sr   = t2 >> 2;             // K row 0..63
    const int sc4  = (t2 & 3) * 16;       // K col chunk
    const int vq   = t2 & 15;             // V key-quad
    const int vdb  = (t2 >> 4) * 4;       // V d block
    const int ctw  = vq >> 2, qdw = vq & 3;
    const int keyp = (ctw >> 1) * 32 + qdw * 8 + (ctw & 1) * 4;  // frag-major key'

    const float* Kbase = Kg + (size_t)bh * SQ * DD;
    const float* Vbase = Vg + (size_t)bh * SQ * DD;
    // mask: each wave covers exactly its own 32 rows x 32 keys quarter per tile
    const unsigned char* mbase = maskg
        + (size_t)(qBase + qw * 32 + (lane >> 1)) * SQ + kh * 32 + (lane & 1) * 16;

    // ---- prologue: stage tile 0 ----
    if (isK) {
        const float* ks = Kbase + (size_t)sr * DD + sc4;
        float4 x0 = *(const float4*)(ks),     x1 = *(const float4*)(ks + 4);
        float4 x2 = *(const float4*)(ks + 8), x3 = *(const float4*)(ks + 12);
        union { f16x8 v; f16x2 p[4]; } y0, y1;
        y0.p[0] = PKRTZ(x0.x, x0.y); y0.p[1] = PKRTZ(x0.z, x0.w);
        y0.p[2] = PKRTZ(x1.x, x1.y); y0.p[3] = PKRTZ(x1.z, x1.w);
        y1.p[0] = PKRTZ(x2.x, x2.y); y1.p[1] = PKRTZ(x2.z, x2.w);
        y1.p[2] = PKRTZ(x3.x, x3.y); y1.p[3] = PKRTZ(x3.z, x3.w);
        *(f16x8*)&smem[sr * LDW + sc4]     = y0.v;
        *(f16x8*)&smem[sr * LDW + sc4 + 8] = y1.v;
    } else {
        const float* vb = Vbase + (size_t)(vq * 4) * DD + vdb;
        float4 v0 = *(const float4*)(vb);
        float4 v1 = *(const float4*)(vb + DD);
        float4 v2 = *(const float4*)(vb + 2 * DD);
        float4 v3 = *(const float4*)(vb + 3 * DD);
        _Float16* VT = smem + 2 * BUFH;
        union { f16x4 v; f16x2 p[2]; } t;
        t.p[0] = PKRTZ(v0.x, v1.x); t.p[1] = PKRTZ(v2.x, v3.x);
        *(f16x4*)&VT[(vdb + 0) * LDW + keyp] = t.v;
        t.p[0] = PKRTZ(v0.y, v1.y); t.p[1] = PKRTZ(v2.y, v3.y);
        *(f16x4*)&VT[(vdb + 1) * LDW + keyp] = t.v;
        t.p[0] = PKRTZ(v0.z, v1.z); t.p[1] = PKRTZ(v2.z, v3.z);
        *(f16x4*)&VT[(vdb + 2) * LDW + keyp] = t.v;
        t.p[0] = PKRTZ(v0.w, v1.w); t.p[1] = PKRTZ(v2.w, v3.w);
        *(f16x4*)&VT[(vdb + 3) * LDW + keyp] = t.v;
    }

    // ---- one-shot mask scan: bit t of tmbits = "tile t has any masked elem
    //      in this wave's rows x keys quarter". Removes per-iter mask VMEM. ----
    unsigned tmbits = 0;
    for (int t = 0; t < NT; ++t) {
        uint4 m = *(const uint4*)(mbase + t * BK);
        if (__any((int)(m.x | m.y | m.z | m.w))) tmbits |= (1u << t);
    }
    __syncthreads();

#pragma unroll 2
    for (int kt = 0; kt < NT; ++kt) {
        const int cur = kt & 1;
        const bool more = (kt + 1 < NT);
        _Float16* Kc = smem + cur * BUFH;
        _Float16* Vc = smem + 2 * BUFH + cur * BUFH;

        // ---- register prefetch of next tile (K xor V per wave role) ----
        float4 x0, x1, x2, x3;
        if (more) {
            const int k0n = (kt + 1) * BK;
            if (isK) {
                const float* ks = Kbase + (size_t)(k0n + sr) * DD + sc4;
                x0 = *(const float4*)(ks);     x1 = *(const float4*)(ks + 4);
                x2 = *(const float4*)(ks + 8); x3 = *(const float4*)(ks + 12);
            } else {
                const float* vb = Vbase + (size_t)(k0n + vq * 4) * DD + vdb;
                x0 = *(const float4*)(vb);          x1 = *(const float4*)(vb + DD);
                x2 = *(const float4*)(vb + 2 * DD); x3 = *(const float4*)(vb + 3 * DD);
            }
        }

        // ---- S^T = K*Q^T over this wave's 32-key half (4 ds_reads, 8 MFMA) ----
        f32x4 sA[2][2];   // [qg][c]: keys kh*32 + c*16 + quad*4 + r, q = l16
#pragma unroll
        for (int c = 0; c < 2; ++c) {
            const int krow = (kh * 2 + c) * 16 + l16;
            f16x8 kf0 = *(const f16x8*)&Kc[krow * LDW + quad * 8];
            f16x8 kf1 = *(const f16x8*)&Kc[krow * LDW + 32 + quad * 8];
#pragma unroll
            for (int qg = 0; qg < 2; ++qg) {
                f32x4 cc = (f32x4){0.f, 0.f, 0.f, 0.f};
                cc = MFMA32(kf0, qf[qg][0], cc);
                cc = MFMA32(kf1, qf[qg][1], cc);
                sA[qg][c] = cc;
            }
        }

        // ---- mask (rare slow path; scalar bit-test, wave-uniform) ----
        if ((tmbits >> kt) & 1u) {
#pragma unroll
            for (int qg = 0; qg < 2; ++qg) {
                const size_t qq = (size_t)(qBase + qw * 32 + qg * 16 + l16) * SQ;
#pragma unroll
                for (int c = 0; c < 2; ++c)
#pragma unroll
                    for (int r = 0; r < 4; ++r) {
                        const int kg = kt * BK + kh * 32 + c * 16 + quad * 4 + r;
                        if (maskg[qq + kg]) sA[qg][c][r] = MASKED;
                    }
            }
        }

        // ---- softmax numerators: raw exp2 (log2e folded into QSCALE), packed cvt ----
        union { f16x8 v; f16x2 p[4]; } pf[2];
#pragma unroll
        for (int qg = 0; qg < 2; ++qg) {
            float e0 = EXP2F(sA[qg][0][0]), e1 = EXP2F(sA[qg][0][1]);
            float e2 = EXP2F(sA[qg][0][2]), e3 = EXP2F(sA[qg][0][3]);
            float e4 = EXP2F(sA[qg][1][0]), e5 = EXP2F(sA[qg][1][1]);
            float e6 = EXP2F(sA[qg][1][2]), e7 = EXP2F(sA[qg][1][3]);
            lsum[qg] += ((e0 + e1) + (e2 + e3)) + ((e4 + e5) + (e6 + e7));
            pf[qg].p[0] = PKRTZ(e0, e1); pf[qg].p[1] = PKRTZ(e2, e3);
            pf[qg].p[2] = PKRTZ(e4, e5); pf[qg].p[3] = PKRTZ(e6, e7);
        }

        // ---- P*V with 16x16x32: Vt permutation already matches the x32 B-frag ----
#pragma unroll
        for (int dt = 0; dt < 4; ++dt) {
            f16x8 vv = *(const f16x8*)&Vc[(dt * 16 + l16) * LDW + kh * 32 + quad * 8];
            acc[0][dt] = MFMA32(pf[0].v, vv, acc[0][dt]);
            acc[1][dt] = MFMA32(pf[1].v, vv, acc[1][dt]);
        }

        // ---- stage prefetched tile into the other buffer ----
        if (more) {
            _Float16* Kn = smem + (cur ^ 1) * BUFH;
            _Float16* Vn = smem + 2 * BUFH + (cur ^ 1) * BUFH;
            if (isK) {
                union { f16x8 v; f16x2 p[4]; } y0, y1;
                y0.p[0] = PKRTZ(x0.x, x0.y); y0.p[1] = PKRTZ(x0.z, x0.w);
                y0.p[2] = PKRTZ(x1.x, x1.y); y0.p[3] = PKRTZ(x1.z, x1.w);
                y1.p[0] = PKRTZ(x2.x, x2.y); y1.p[1] = PKRTZ(x2.z, x2.w);
                y1.p[2] = PKRTZ(x3.x, x3.y); y1.p[3] = PKRTZ(x3.z, x3.w);
                *(f16x8*)&Kn[sr * LDW + sc4]     = y0.v;
                *(f16x8*)&Kn[sr * LDW + sc4 + 8] = y1.v;
            } else {
                union { f16x4 v; f16x2 p[2]; } t;
                t.p[0] = PKRTZ(x0.x, x1.x); t.p[1] = PKRTZ(x2.x, x3.x);
                *(f16x4*)&Vn[(vdb + 0) * LDW + keyp] = t.v;
                t.p[0] = PKRTZ(x0.y, x1.y); t.p[1] = PKRTZ(x2.y, x3.y);
                *(f16x4*)&Vn[(vdb + 1) * LDW + keyp] = t.v;
                t.p[0] = PKRTZ(x0.z, x1.z); t.p[1] = PKRTZ(x2.z, x3.z);
                *(f16x4*)&Vn[(vdb + 2) * LDW + keyp] = t.v;
                t.p[0] = PKRTZ(x0.w, x1.w); t.p[1] = PKRTZ(x2.w, x3.w);
                *(f16x4*)&Vn[(vdb + 3) * LDW + keyp] = t.v;
            }
        }
        __syncthreads();
    }

    // ---- epilogue: merge the two key-half partials via LDS, normalize, store ----
    float* M = (float*)smem;   // 8 (qw,qg) slots x 4 dt x 64 lanes x f32x4 = 32 KB, + lsum
    const int slot = qw * 2;
    if (kh) {
#pragma unroll
        for (int qg = 0; qg < 2; ++qg) {
#pragma unroll
            for (int dt = 0; dt < 4; ++dt)
                *(f32x4*)&M[(((slot + qg) * 4 + dt) * 64 + lane) * 4] = acc[qg][dt];
            M[8192 + (slot + qg) * 64 + lane] = lsum[qg];
        }
    }
    __syncthreads();
    if (!kh) {
#pragma unroll
        for (int qg = 0; qg < 2; ++qg) {
#pragma unroll
            for (int dt = 0; dt < 4; ++dt)
                acc[qg][dt] += *(const f32x4*)&M[(((slot + qg) * 4 + dt) * 64 + lane) * 4];
            float l = lsum[qg] + M[8192 + (slot + qg) * 64 + lane];
            l += __shfl_xor(l, 16);
            l += __shfl_xor(l, 32);
            float* ob = Og + ((size_t)bh * SQ + qBase + qw * 32 + qg * 16) * DD;
#pragma unroll
            for (int r = 0; r < 4; ++r) {
                const float inv = 1.0f / __shfl(l, quad * 4 + r);
                const int qr = quad * 4 + r;
#pragma unroll
                for (int dt = 0; dt < 4; ++dt)
                    ob[qr * DD + dt * 16 + l16] = acc[qg][dt][r] * inv;
            }
        }
    }
}

extern "C" void kernel_launch(void* const* d_in, const int* in_sizes, int n_in,
                              void* d_out, int out_size, void* d_ws, size_t ws_size,
                              hipStream_t stream) {
    const float* Q = (const float*)d_in[0];
    const float* K = (const float*)d_in[1];
    const float* V = (const float*)d_in[2];
    const unsigned char* mask = (const unsigned char*)d_in[3];
    float* Out = (float*)d_out;
    attn_fused6<<<dim3(32 * 16), dim3(512), 0, stream>>>(Q, K, V, mask, Out);
}

// Round 12
// 153.863 us; speedup vs baseline: 2.4170x; 2.4170x over previous
//
#include <hip/hip_runtime.h>

#define SQ   2048
#define DD   64
#define BK   64
#define BQ   128
#define LDW  72
#define NT   32   // SQ / BK

typedef _Float16 f16x8 __attribute__((ext_vector_type(8)));
typedef _Float16 f16x4 __attribute__((ext_vector_type(4)));
typedef _Float16 f16x2 __attribute__((ext_vector_type(2)));
typedef float    f32x4 __attribute__((ext_vector_type(4)));

#if __has_builtin(__builtin_amdgcn_exp2f)
#define EXP2F(x) __builtin_amdgcn_exp2f(x)
#else
#define EXP2F(x) exp2f(x)
#endif

// __builtin_amdgcn_cvt_pkrtz returns __fp16x2; bit-cast to our _Float16x2.
static __device__ __forceinline__ f16x2 PKRTZ(float a, float b) {
    typedef __fp16 fp16x2_t __attribute__((ext_vector_type(2)));
    union { fp16x2_t i; f16x2 o; } u;
    u.i = __builtin_amdgcn_cvt_pkrtz(a, b);
    return u.o;
}
#define MFMA32(a, b, c) __builtin_amdgcn_mfma_f32_16x16x32_f16((a), (b), (c), 0, 0, 0)

// R0 structure (256 threads, 4 waves, proven 86 us/dispatch, VGPR 104) with
// three instruction-diet grafts: PV on 16x16x32 MFMA (halves PV matrix cycles),
// exp2 with log2e folded into the Q scale, packed cvt_pkrtz conversions.
__global__ __launch_bounds__(256, 2)
void attn_fused7(const float* __restrict__ Qg,
                 const float* __restrict__ Kg,
                 const float* __restrict__ Vg,
                 const unsigned char* __restrict__ maskg,
                 float* __restrict__ Og)
{
    __shared__ _Float16 Kl[2][BK * LDW];   // [buf][key][d]
    __shared__ _Float16 Vt[2][DD * LDW];   // [buf][d][key'] (frag-major permuted)

    const int tid  = threadIdx.x;
    const int lane = tid & 63;
    const int w    = tid >> 6;
    const int quad = lane >> 4;
    const int l16  = lane & 15;

    // XCD swizzle: all 16 q-tiles of one (b,h) land on one XCD -> K/V L2 reuse.
    const int n     = blockIdx.x;             // 512 blocks
    const int bh    = (n & 7) + 8 * ((n >> 3) & 3);
    const int qtile = n >> 5;                 // 0..15
    const int qBase = qtile * BQ;

    // dk = key length (2048). log2(e) folded so exp(x*s) == exp2(x*QSCALE).
    const float QSCALE = 0.02209708691207961f * 1.4426950408889634f;
    const float MASKED = -1e10f * (0.02209708691207961f * 1.4426950408889634f);

    // ---- Q fragments, pre-scaled. qg in {0,1}: q = qBase + w*32 + qg*16 + l16 ----
    f16x8 qf[2][2];
#pragma unroll
    for (int qg = 0; qg < 2; ++qg) {
        const float* qrow = Qg + ((size_t)bh * SQ + qBase + w * 32 + qg * 16 + l16) * DD;
#pragma unroll
        for (int h = 0; h < 2; ++h) {
            float4 a = *(const float4*)(qrow + h * 32 + quad * 8);
            float4 b = *(const float4*)(qrow + h * 32 + quad * 8 + 4);
            union { f16x8 v; f16x2 p[4]; } u;
            u.p[0] = PKRTZ(a.x * QSCALE, a.y * QSCALE);
            u.p[1] = PKRTZ(a.z * QSCALE, a.w * QSCALE);
            u.p[2] = PKRTZ(b.x * QSCALE, b.y * QSCALE);
            u.p[3] = PKRTZ(b.z * QSCALE, b.w * QSCALE);
            qf[qg][h] = u.v;
        }
    }

    f32x4 acc[2][4];
#pragma unroll
    for (int qg = 0; qg < 2; ++qg)
#pragma unroll
        for (int d = 0; d < 4; ++d) acc[qg][d] = (f32x4){0.f, 0.f, 0.f, 0.f};
    float lsum[2] = {0.f, 0.f};   // per-lane partial softmax denominators

    // staging maps (every thread stages K and V, exactly as R0)
    const int sr  = tid >> 2;             // K row 0..63
    const int sc4 = (tid & 3) * 16;       // K col chunk (halves)
    const int vq  = tid & 15;             // V key-quad 0..15 (keys vq*4..vq*4+3)
    const int vdb = (tid >> 4) * 4;       // V d block
    // permuted key' base: key=ct*16+quad*4+r -> key'=(ct>>1)*32 + quad*8 + (ct&1)*4 + r
    const int ctw  = vq >> 2, qdw = vq & 3;
    const int keyp = (ctw >> 1) * 32 + qdw * 8 + (ctw & 1) * 4;

    const float* Kbase = Kg + (size_t)bh * SQ * DD;
    const float* Vbase = Vg + (size_t)bh * SQ * DD;
    const unsigned char* mbase = maskg + (size_t)(qBase + (tid >> 1)) * SQ + (tid & 1) * 32;

    // ---- prologue: stage tile 0 ----
    {
        const float* ks = Kbase + (size_t)sr * DD + sc4;
        float4 k0v = *(const float4*)(ks + 0), k1v = *(const float4*)(ks + 4);
        float4 k2v = *(const float4*)(ks + 8), k3v = *(const float4*)(ks + 12);
        float4 v0, v1, v2, v3;
        v0 = *(const float4*)(Vbase + (size_t)(vq * 4 + 0) * DD + vdb);
        v1 = *(const float4*)(Vbase + (size_t)(vq * 4 + 1) * DD + vdb);
        v2 = *(const float4*)(Vbase + (size_t)(vq * 4 + 2) * DD + vdb);
        v3 = *(const float4*)(Vbase + (size_t)(vq * 4 + 3) * DD + vdb);
        union { f16x8 v; f16x2 p[4]; } y0, y1;
        y0.p[0] = PKRTZ(k0v.x, k0v.y); y0.p[1] = PKRTZ(k0v.z, k0v.w);
        y0.p[2] = PKRTZ(k1v.x, k1v.y); y0.p[3] = PKRTZ(k1v.z, k1v.w);
        y1.p[0] = PKRTZ(k2v.x, k2v.y); y1.p[1] = PKRTZ(k2v.z, k2v.w);
        y1.p[2] = PKRTZ(k3v.x, k3v.y); y1.p[3] = PKRTZ(k3v.z, k3v.w);
        *(f16x8*)&Kl[0][sr * LDW + sc4]     = y0.v;
        *(f16x8*)&Kl[0][sr * LDW + sc4 + 8] = y1.v;
        union { f16x4 v; f16x2 p[2]; } t;
        t.p[0] = PKRTZ(v0.x, v1.x); t.p[1] = PKRTZ(v2.x, v3.x);
        *(f16x4*)&Vt[0][(vdb + 0) * LDW + keyp] = t.v;
        t.p[0] = PKRTZ(v0.y, v1.y); t.p[1] = PKRTZ(v2.y, v3.y);
        *(f16x4*)&Vt[0][(vdb + 1) * LDW + keyp] = t.v;
        t.p[0] = PKRTZ(v0.z, v1.z); t.p[1] = PKRTZ(v2.z, v3.z);
        *(f16x4*)&Vt[0][(vdb + 2) * LDW + keyp] = t.v;
        t.p[0] = PKRTZ(v0.w, v1.w); t.p[1] = PKRTZ(v2.w, v3.w);
        *(f16x4*)&Vt[0][(vdb + 3) * LDW + keyp] = t.v;
    }
    uint4 ma = *(const uint4*)(mbase), mb = *(const uint4*)(mbase + 16);
    int tm = __syncthreads_or((int)(ma.x | ma.y | ma.z | ma.w | mb.x | mb.y | mb.z | mb.w));

#pragma unroll 2
    for (int kt = 0; kt < NT; ++kt) {
        const int cur = kt & 1;
        const bool more = (kt + 1 < NT);

        // ---- register prefetch of next tile ----
        float4 kx[4], vx[4]; uint4 ma2 = {0,0,0,0}, mb2 = {0,0,0,0};
        if (more) {
            const int k0n = (kt + 1) * BK;
            const float* ks = Kbase + (size_t)(k0n + sr) * DD + sc4;
            kx[0] = *(const float4*)(ks + 0);  kx[1] = *(const float4*)(ks + 4);
            kx[2] = *(const float4*)(ks + 8);  kx[3] = *(const float4*)(ks + 12);
            const float* vb = Vbase + (size_t)(k0n + vq * 4) * DD + vdb;
            vx[0] = *(const float4*)(vb);           vx[1] = *(const float4*)(vb + DD);
            vx[2] = *(const float4*)(vb + 2 * DD);  vx[3] = *(const float4*)(vb + 3 * DD);
            ma2 = *(const uint4*)(mbase + k0n);
            mb2 = *(const uint4*)(mbase + k0n + 16);
        }

        // ---- S^T = K*Q^T : per ct read K-frags once, use for both q-groups ----
        f32x4 sA[4], sB[4];
#pragma unroll
        for (int ct = 0; ct < 4; ++ct) {
            f16x8 kf0 = *(const f16x8*)&Kl[cur][(ct * 16 + l16) * LDW + quad * 8];
            f16x8 kf1 = *(const f16x8*)&Kl[cur][(ct * 16 + l16) * LDW + 32 + quad * 8];
            f32x4 c0 = (f32x4){0.f, 0.f, 0.f, 0.f};
            c0 = MFMA32(kf0, qf[0][0], c0);
            c0 = MFMA32(kf1, qf[0][1], c0);
            sA[ct] = c0;
            f32x4 c1 = (f32x4){0.f, 0.f, 0.f, 0.f};
            c1 = MFMA32(kf0, qf[1][0], c1);
            c1 = MFMA32(kf1, qf[1][1], c1);
            sB[ct] = c1;
        }

        // ---- mask (rare slow path) ----
        if (tm) {
#pragma unroll
            for (int qg = 0; qg < 2; ++qg) {
                const int qgq = qBase + w * 32 + qg * 16 + l16;
#pragma unroll
                for (int ct = 0; ct < 4; ++ct)
#pragma unroll
                    for (int r = 0; r < 4; ++r) {
                        const int kg = kt * BK + ct * 16 + quad * 4 + r;
                        if (maskg[(size_t)qgq * SQ + kg]) {
                            if (qg == 0) sA[ct][r] = MASKED; else sB[ct][r] = MASKED;
                        }
                    }
            }
        }

        // ---- softmax numerators: raw exp2 (log2e pre-folded), packed cvt.
        //      pf[qg][cp] = A-frag for PV x32: concat(P[ct=2cp], P[ct=2cp+1]) ----
        union { f16x8 v; f16x2 p[4]; } pfA[2], pfB[2];
        float ls0 = 0.f, ls1 = 0.f;
#pragma unroll
        for (int ct = 0; ct < 4; ++ct) {
            float a0 = EXP2F(sA[ct][0]), a1 = EXP2F(sA[ct][1]);
            float a2 = EXP2F(sA[ct][2]), a3 = EXP2F(sA[ct][3]);
            float b0 = EXP2F(sB[ct][0]), b1 = EXP2F(sB[ct][1]);
            float b2 = EXP2F(sB[ct][2]), b3 = EXP2F(sB[ct][3]);
            ls0 += (a0 + a1) + (a2 + a3);
            ls1 += (b0 + b1) + (b2 + b3);
            pfA[ct >> 1].p[(ct & 1) * 2 + 0] = PKRTZ(a0, a1);
            pfA[ct >> 1].p[(ct & 1) * 2 + 1] = PKRTZ(a2, a3);
            pfB[ct >> 1].p[(ct & 1) * 2 + 0] = PKRTZ(b0, b1);
            pfB[ct >> 1].p[(ct & 1) * 2 + 1] = PKRTZ(b2, b3);
        }
        lsum[0] += ls0; lsum[1] += ls1;

        // ---- P*V with 16x16x32: Vt key' permutation matches the x32 B-frag ----
#pragma unroll
        for (int dt = 0; dt < 4; ++dt) {
#pragma unroll
            for (int cp = 0; cp < 2; ++cp) {
                f16x8 vv = *(const f16x8*)&Vt[cur][(dt * 16 + l16) * LDW + cp * 32 + quad * 8];
                acc[0][dt] = MFMA32(pfA[cp].v, vv, acc[0][dt]);
                acc[1][dt] = MFMA32(pfB[cp].v, vv, acc[1][dt]);
            }
        }

        // ---- stage prefetched tile ----
        if (more) {
            union { f16x8 v; f16x2 p[4]; } y0, y1;
            y0.p[0] = PKRTZ(kx[0].x, kx[0].y); y0.p[1] = PKRTZ(kx[0].z, kx[0].w);
            y0.p[2] = PKRTZ(kx[1].x, kx[1].y); y0.p[3] = PKRTZ(kx[1].z, kx[1].w);
            y1.p[0] = PKRTZ(kx[2].x, kx[2].y); y1.p[1] = PKRTZ(kx[2].z, kx[2].w);
            y1.p[2] = PKRTZ(kx[3].x, kx[3].y); y1.p[3] = PKRTZ(kx[3].z, kx[3].w);
            *(f16x8*)&Kl[cur ^ 1][sr * LDW + sc4]     = y0.v;
            *(f16x8*)&Kl[cur ^ 1][sr * LDW + sc4 + 8] = y1.v;
            union { f16x4 v; f16x2 p[2]; } t;
            t.p[0] = PKRTZ(vx[0].x, vx[1].x); t.p[1] = PKRTZ(vx[2].x, vx[3].x);
            *(f16x4*)&Vt[cur ^ 1][(vdb + 0) * LDW + keyp] = t.v;
            t.p[0] = PKRTZ(vx[0].y, vx[1].y); t.p[1] = PKRTZ(vx[2].y, vx[3].y);
            *(f16x4*)&Vt[cur ^ 1][(vdb + 1) * LDW + keyp] = t.v;
            t.p[0] = PKRTZ(vx[0].z, vx[1].z); t.p[1] = PKRTZ(vx[2].z, vx[3].z);
            *(f16x4*)&Vt[cur ^ 1][(vdb + 2) * LDW + keyp] = t.v;
            t.p[0] = PKRTZ(vx[0].w, vx[1].w); t.p[1] = PKRTZ(vx[2].w, vx[3].w);
            *(f16x4*)&Vt[cur ^ 1][(vdb + 3) * LDW + keyp] = t.v;
        }
        // single barrier per iter; doubles as next tile's mask any-reduce
        tm = __syncthreads_or((int)(ma2.x | ma2.y | ma2.z | ma2.w | mb2.x | mb2.y | mb2.z | mb2.w));
    }

    // ---- epilogue: reduce l across quads (only cross-lane ops in the kernel) ----
#pragma unroll
    for (int qg = 0; qg < 2; ++qg) {
        float l = lsum[qg];
        l += __shfl_xor(l, 16);
        l += __shfl_xor(l, 32);
        float lrow[4];
#pragma unroll
        for (int r = 0; r < 4; ++r) lrow[r] = __shfl(l, quad * 4 + r);
        float* ob = Og + ((size_t)bh * SQ + qBase + w * 32 + qg * 16) * DD;
#pragma unroll
        for (int r = 0; r < 4; ++r) {
            const float inv = 1.0f / lrow[r];
            const int qr = quad * 4 + r;
#pragma unroll
            for (int dt = 0; dt < 4; ++dt)
                ob[qr * DD + dt * 16 + l16] = acc[qg][dt][r] * inv;
        }
    }
}

extern "C" void kernel_launch(void* const* d_in, const int* in_sizes, int n_in,
                              void* d_out, int out_size, void* d_ws, size_t ws_size,
                              hipStream_t stream) {
    const float* Q = (const float*)d_in[0];
    const float* K = (const float*)d_in[1];
    const float* V = (const float*)d_in[2];
    const unsigned char* mask = (const unsigned char*)d_in[3];
    float* Out = (float*)d_out;
    attn_fused7<<<dim3(32 * 16), dim3(256), 0, stream>>>(Q, K, V, mask, Out);
}